// Round 1
// baseline (585.995 us; speedup 1.0000x reference)
//
#include <hip/hip_runtime.h>

typedef __attribute__((ext_vector_type(8))) short bf16x8;   // MFMA A/B frag (8 bf16)
typedef __attribute__((ext_vector_type(4))) float f32x4;    // MFMA C/D frag
typedef __attribute__((ext_vector_type(4))) int int4v;      // 16B load/store
typedef __attribute__((ext_vector_type(8))) unsigned short u16x8;
typedef __attribute__((ext_vector_type(4))) unsigned short u16x4;

__device__ __forceinline__ unsigned short f2bf(float f) {
  unsigned u = __builtin_bit_cast(unsigned, f);
  return (unsigned short)((u + 0x7fffu + ((u >> 16) & 1u)) >> 16);
}

// ---------------- convert x fp32 -> bf16, 8 elems/thread ----------------
__global__ __launch_bounds__(256) void k_cvt(const float* __restrict__ x,
                                             unsigned short* __restrict__ xb) {
  int i = blockIdx.x * 256 + threadIdx.x;
  const float4* s = (const float4*)x;
  float4 a = s[2 * i], b = s[2 * i + 1];
  u16x8 o;
  o[0] = f2bf(a.x); o[1] = f2bf(a.y); o[2] = f2bf(a.z); o[3] = f2bf(a.w);
  o[4] = f2bf(b.x); o[5] = f2bf(b.y); o[6] = f2bf(b.z); o[7] = f2bf(b.w);
  *(u16x8*)(xb + 8 * (size_t)i) = o;
}

// ------------- transpose+convert weight [K][N] f32 -> [N][K] bf16 -------------
__global__ __launch_bounds__(256) void k_wT(const float* __restrict__ w,
                                            unsigned short* __restrict__ wT,
                                            int Nn, int Kk) {
  __shared__ float tile[32][33];
  const int k0 = blockIdx.x * 32, n0 = blockIdx.y * 32;
  const int t = threadIdx.x;
  const int i = t >> 3, j = (t & 7) * 4;
  float4 v = *(const float4*)(w + (size_t)(k0 + i) * Nn + n0 + j);
  tile[i][j] = v.x; tile[i][j + 1] = v.y; tile[i][j + 2] = v.z; tile[i][j + 3] = v.w;
  __syncthreads();
  const int n = i, k4 = j;
  u16x4 o;
  o[0] = f2bf(tile[k4 + 0][n]); o[1] = f2bf(tile[k4 + 1][n]);
  o[2] = f2bf(tile[k4 + 2][n]); o[3] = f2bf(tile[k4 + 3][n]);
  *(u16x4*)(wT + (size_t)(n0 + n) * Kk + k0 + k4) = o;
}

// ---------------- GEMM: C[M,Nx] = A[M,1024] @ Bt[Nx,1024]^T + bias ----------------
// EPI 0: fp32 row-major out.  EPI 1: scatter to Q/K/V bf16 (scale on Q,K).
template <int EPI>
__global__ __launch_bounds__(256) void k_gemm(const unsigned short* __restrict__ A,
                                              const unsigned short* __restrict__ Bt,
                                              const float* __restrict__ bias, int Nx,
                                              float* __restrict__ outF,
                                              unsigned short* __restrict__ Qb,
                                              unsigned short* __restrict__ Kb,
                                              unsigned short* __restrict__ Vb) {
  __shared__ unsigned short As[128][40];  // +8 pad keeps 16B align, kills frag-read conflicts
  __shared__ unsigned short Bs[128][40];
  const int t = threadIdx.x;
  const int brow = blockIdx.x * 128, bcol = blockIdx.y * 128;
  const int lane = t & 63, wid = t >> 6;
  const int wr = (wid >> 1) * 64, wc = (wid & 1) * 64;
  const int g = lane >> 4, qr = lane & 15;
  const f32x4 fzero = {0.f, 0.f, 0.f, 0.f};
  f32x4 acc[4][4];
#pragma unroll
  for (int i = 0; i < 4; ++i)
#pragma unroll
    for (int n = 0; n < 4; ++n) acc[i][n] = fzero;
  const int r0 = t >> 2, koff = (t & 3) * 8;
  const unsigned short* Ap = A + (size_t)(brow + r0) * 1024 + koff;
  const unsigned short* Bp = Bt + (size_t)(bcol + r0) * 1024 + koff;
  for (int kt = 0; kt < 32; ++kt) {
    const int k0 = kt * 32;
    int4v av0 = *(const int4v*)(Ap + k0);
    int4v av1 = *(const int4v*)(Ap + 64 * 1024 + k0);
    int4v bv0 = *(const int4v*)(Bp + k0);
    int4v bv1 = *(const int4v*)(Bp + 64 * 1024 + k0);
    __syncthreads();
    *(int4v*)&As[r0][koff] = av0;
    *(int4v*)&As[r0 + 64][koff] = av1;
    *(int4v*)&Bs[r0][koff] = bv0;
    *(int4v*)&Bs[r0 + 64][koff] = bv1;
    __syncthreads();
    bf16x8 a[4], b[4];
#pragma unroll
    for (int i = 0; i < 4; ++i) a[i] = *(const bf16x8*)&As[wr + i * 16 + qr][g * 8];
#pragma unroll
    for (int n = 0; n < 4; ++n) b[n] = *(const bf16x8*)&Bs[wc + n * 16 + qr][g * 8];
#pragma unroll
    for (int i = 0; i < 4; ++i)
#pragma unroll
      for (int n = 0; n < 4; ++n)
        acc[i][n] = __builtin_amdgcn_mfma_f32_16x16x32_bf16(a[i], b[n], acc[i][n], 0, 0, 0);
  }
#pragma unroll
  for (int i = 0; i < 4; ++i) {
#pragma unroll
    for (int n = 0; n < 4; ++n) {
      const int col = bcol + wc + n * 16 + qr;
      const float bv = bias[col];
#pragma unroll
      for (int r = 0; r < 4; ++r) {
        const int row = brow + wr + i * 16 + g * 4 + r;
        const float v = acc[i][n][r] + bv;
        if constexpr (EPI == 0) {
          outF[(size_t)row * Nx + col] = v;
        } else {
          const int bb = row >> 11, tkn = row & 2047;
          const unsigned c = (unsigned)col;
          const unsigned h = c / 192u;
          const unsigned rem = c - h * 192u;
          const unsigned which = rem >> 6, d = rem & 63u;
          const float sc = (which < 2u) ? 0.35355339059327373f : 1.0f;
          const unsigned short u = f2bf(v * sc);
          unsigned short* dst = (which == 0u) ? Qb : ((which == 1u) ? Kb : Vb);
          dst[(size_t)(((unsigned)bb * 16u + h) * 2048u + (unsigned)tkn) * 64u + d] = u;
        }
      }
    }
  }
}

// ---------------- V transpose: [bh][n][64] -> [bh][64][n] (bf16) ----------------
__global__ __launch_bounds__(256) void k_vT(const unsigned short* __restrict__ Vb,
                                            unsigned short* __restrict__ Vt) {
  const int bid = blockIdx.x;
  const int bh = bid >> 5, n0 = (bid & 31) * 64;
  const int t = threadIdx.x, d = t & 63, rep = t >> 6;
  const unsigned short* src = Vb + (size_t)(bh * 2048 + n0 + rep * 16) * 64 + d;
  unsigned short* dst = Vt + (size_t)(bh * 64 + d) * 2048 + n0 + rep * 16;
  unsigned short vals[16];
#pragma unroll
  for (int jj = 0; jj < 16; ++jj) vals[jj] = src[(size_t)jj * 64];  // 128B coalesced per step
  u16x8 p0, p1;
#pragma unroll
  for (int jj = 0; jj < 8; ++jj) { p0[jj] = vals[jj]; p1[jj] = vals[8 + jj]; }
  *(u16x8*)(dst) = p0;
  *(u16x8*)(dst + 8) = p1;
}

// ---------------- flash attention, swapped QK^T, 16 q-rows per wave ----------------
__global__ __launch_bounds__(256) void k_attn(const unsigned short* __restrict__ Qb,
                                              const unsigned short* __restrict__ Kb,
                                              const unsigned short* __restrict__ Vt,
                                              unsigned short* __restrict__ Ao) {
  const int qt = blockIdx.x, bh = blockIdx.y;
  const int t = threadIdx.x, lane = t & 63, w = t >> 6;
  const int g = lane >> 4, q = lane & 15;
  const int q0 = qt * 64 + w * 16;
  const unsigned short* Qbase = Qb + (size_t)(bh * 2048 + q0) * 64;
  const unsigned short* Kbase = Kb + (size_t)bh * 2048 * 64;
  const unsigned short* Vbase = Vt + (size_t)bh * 64 * 2048;
  __shared__ unsigned short Ps[4][640];  // per-wave 16 x 32 P tile, row stride 40 (80B)
  unsigned short* Pw = &Ps[w][0];
  const f32x4 fzero = {0.f, 0.f, 0.f, 0.f};
  // Q as B-operand: col=q (lane&15), k=d
  const bf16x8 qf0 = *(const bf16x8*)(Qbase + q * 64 + g * 8);
  const bf16x8 qf1 = *(const bf16x8*)(Qbase + q * 64 + 32 + g * 8);
  f32x4 o[4];
#pragma unroll
  for (int i = 0; i < 4; ++i) o[i] = fzero;
  float m = -1e30f, l = 0.f;
  for (int j0 = 0; j0 < 2048; j0 += 32) {
    const unsigned short* Krow = Kbase + (size_t)j0 * 64;
    // K as A-operand: row = key (lane&15), k = d
    bf16x8 ka0 = *(const bf16x8*)(Krow + q * 64 + g * 8);
    bf16x8 ka1 = *(const bf16x8*)(Krow + q * 64 + 32 + g * 8);
    bf16x8 kb0 = *(const bf16x8*)(Krow + (16 + q) * 64 + g * 8);
    bf16x8 kb1 = *(const bf16x8*)(Krow + (16 + q) * 64 + 32 + g * 8);
    f32x4 s0 = fzero, s1 = fzero;
    s0 = __builtin_amdgcn_mfma_f32_16x16x32_bf16(ka0, qf0, s0, 0, 0, 0);
    s0 = __builtin_amdgcn_mfma_f32_16x16x32_bf16(ka1, qf1, s0, 0, 0, 0);
    s1 = __builtin_amdgcn_mfma_f32_16x16x32_bf16(kb0, qf0, s1, 0, 0, 0);
    s1 = __builtin_amdgcn_mfma_f32_16x16x32_bf16(kb1, qf1, s1, 0, 0, 0);
    // lane holds S^T: keys {j0+4g+r} (s0), {j0+16+4g+r} (s1) for query q=lane&15
    float mt = fmaxf(fmaxf(fmaxf(s0[0], s0[1]), fmaxf(s0[2], s0[3])),
                     fmaxf(fmaxf(s1[0], s1[1]), fmaxf(s1[2], s1[3])));
    mt = fmaxf(mt, __shfl_xor(mt, 16));
    mt = fmaxf(mt, __shfl_xor(mt, 32));
    const float mnew = fmaxf(m, mt);
    const float alpha = __expf(m - mnew);
    float p[8];
    float ts = 0.f;
#pragma unroll
    for (int r = 0; r < 4; ++r) { p[r] = __expf(s0[r] - mnew); ts += p[r]; }
#pragma unroll
    for (int r = 0; r < 4; ++r) { p[4 + r] = __expf(s1[r] - mnew); ts += p[4 + r]; }
    ts += __shfl_xor(ts, 16);
    ts += __shfl_xor(ts, 32);
    l = l * alpha + ts;
    m = mnew;
    // write P (bf16) to wave-private LDS: row=query q, cols=keys
    asm volatile("" ::: "memory");
    unsigned pk;
    pk = (unsigned)f2bf(p[0]) | ((unsigned)f2bf(p[1]) << 16);
    *(unsigned*)&Pw[q * 40 + 4 * g] = pk;
    pk = (unsigned)f2bf(p[2]) | ((unsigned)f2bf(p[3]) << 16);
    *(unsigned*)&Pw[q * 40 + 4 * g + 2] = pk;
    pk = (unsigned)f2bf(p[4]) | ((unsigned)f2bf(p[5]) << 16);
    *(unsigned*)&Pw[q * 40 + 16 + 4 * g] = pk;
    pk = (unsigned)f2bf(p[6]) | ((unsigned)f2bf(p[7]) << 16);
    *(unsigned*)&Pw[q * 40 + 16 + 4 * g + 2] = pk;
    asm volatile("" ::: "memory");
    // rescale O by alpha (per query row 4g+r)
    const float a0 = __shfl(alpha, 4 * g + 0);
    const float a1 = __shfl(alpha, 4 * g + 1);
    const float a2 = __shfl(alpha, 4 * g + 2);
    const float a3 = __shfl(alpha, 4 * g + 3);
#pragma unroll
    for (int i = 0; i < 4; ++i) { o[i][0] *= a0; o[i][1] *= a1; o[i][2] *= a2; o[i][3] *= a3; }
    // P as A-operand: row=q (lane&15), k=key 8g+j
    const bf16x8 pa = *(const bf16x8*)&Pw[q * 40 + g * 8];
#pragma unroll
    for (int dblk = 0; dblk < 4; ++dblk) {
      const bf16x8 vv = *(const bf16x8*)(Vbase + (size_t)(dblk * 16 + q) * 2048 + j0 + 8 * g);
      o[dblk] = __builtin_amdgcn_mfma_f32_16x16x32_bf16(pa, vv, o[dblk], 0, 0, 0);
    }
  }
  const float linv = 1.0f / l;
  float lr[4];
  lr[0] = __shfl(linv, 4 * g + 0);
  lr[1] = __shfl(linv, 4 * g + 1);
  lr[2] = __shfl(linv, 4 * g + 2);
  lr[3] = __shfl(linv, 4 * g + 3);
  const int bb = bh >> 4, hh = bh & 15;
  unsigned short* ob = Ao + (size_t)(bb * 2048 + q0 + 4 * g) * 1024 + hh * 64 + q;
#pragma unroll
  for (int dblk = 0; dblk < 4; ++dblk)
#pragma unroll
    for (int r = 0; r < 4; ++r)
      ob[(size_t)r * 1024 + dblk * 16] = f2bf(o[dblk][r] * lr[r]);
}

extern "C" void kernel_launch(void* const* d_in, const int* in_sizes, int n_in,
                              void* d_out, int out_size, void* d_ws, size_t ws_size,
                              hipStream_t stream) {
  const float* x = (const float*)d_in[0];
  const float* w_qkv = (const float*)d_in[1];
  const float* b_qkv = (const float*)d_in[2];
  const float* w_proj = (const float*)d_in[3];
  const float* b_proj = (const float*)d_in[4];
  float* out = (float*)d_out;
  char* ws = (char*)d_ws;
  unsigned short* xb = (unsigned short*)(ws);                  // 16 MB  [8192,1024] bf16
  unsigned short* wqkvT = (unsigned short*)(ws + 16777216);    // 6 MB   [3072,1024]
  unsigned short* wprojT = (unsigned short*)(ws + 23068672);   // 2 MB   [1024,1024]
  unsigned short* Qb = (unsigned short*)(ws + 25165824);       // 16 MB  [bh][2048][64]
  unsigned short* Kb = (unsigned short*)(ws + 41943040);       // 16 MB
  unsigned short* Vb = (unsigned short*)(ws + 58720256);       // 16 MB
  unsigned short* Vt = (unsigned short*)(ws + 75497472);       // 16 MB  [bh][64][2048]
  unsigned short* Ao = xb;  // reuse (xb dead after GEMM1)

  hipLaunchKernelGGL(k_cvt, dim3(4096), dim3(256), 0, stream, x, xb);
  hipLaunchKernelGGL(k_wT, dim3(32, 96), dim3(256), 0, stream, w_qkv, wqkvT, 3072, 1024);
  hipLaunchKernelGGL(k_wT, dim3(32, 32), dim3(256), 0, stream, w_proj, wprojT, 1024, 1024);
  hipLaunchKernelGGL((k_gemm<1>), dim3(64, 24), dim3(256), 0, stream,
                     xb, wqkvT, b_qkv, 3072, (float*)nullptr, Qb, Kb, Vb);
  hipLaunchKernelGGL(k_vT, dim3(2048), dim3(256), 0, stream, Vb, Vt);
  hipLaunchKernelGGL(k_attn, dim3(32, 64), dim3(256), 0, stream, Qb, Kb, Vt, Ao);
  hipLaunchKernelGGL((k_gemm<0>), dim3(64, 8), dim3(256), 0, stream,
                     Ao, wprojT, b_proj, 1024, out,
                     (unsigned short*)nullptr, (unsigned short*)nullptr, (unsigned short*)nullptr);
}

// Round 2
// 282.944 us; speedup vs baseline: 2.0711x; 2.0711x over previous
//
#include <hip/hip_runtime.h>

typedef __attribute__((ext_vector_type(8))) short bf16x8;   // MFMA A/B frag (8 bf16)
typedef __attribute__((ext_vector_type(4))) float f32x4;    // MFMA C/D frag
typedef __attribute__((ext_vector_type(4))) int int4v;      // 16B load/store
typedef __attribute__((ext_vector_type(8))) unsigned short u16x8;
typedef __attribute__((ext_vector_type(4))) unsigned short u16x4;

__device__ __forceinline__ unsigned short f2bf(float f) {
  unsigned u = __builtin_bit_cast(unsigned, f);
  return (unsigned short)((u + 0x7fffu + ((u >> 16) & 1u)) >> 16);
}

__device__ __forceinline__ void gl_lds16(const void* g, void* l) {
  __builtin_amdgcn_global_load_lds((const __attribute__((address_space(1))) unsigned*)g,
                                   (__attribute__((address_space(3))) unsigned*)l, 16, 0, 0);
}

// ---------------- convert x fp32 -> bf16, 8 elems/thread ----------------
__global__ __launch_bounds__(256) void k_cvt(const float* __restrict__ x,
                                             unsigned short* __restrict__ xb) {
  int i = blockIdx.x * 256 + threadIdx.x;
  const float4* s = (const float4*)x;
  float4 a = s[2 * i], b = s[2 * i + 1];
  u16x8 o;
  o[0] = f2bf(a.x); o[1] = f2bf(a.y); o[2] = f2bf(a.z); o[3] = f2bf(a.w);
  o[4] = f2bf(b.x); o[5] = f2bf(b.y); o[6] = f2bf(b.z); o[7] = f2bf(b.w);
  *(u16x8*)(xb + 8 * (size_t)i) = o;
}

// ------------- transpose+convert weight [K][N] f32 -> [N][K] bf16 -------------
__global__ __launch_bounds__(256) void k_wT(const float* __restrict__ w,
                                            unsigned short* __restrict__ wT,
                                            int Nn, int Kk) {
  __shared__ float tile[32][33];
  const int k0 = blockIdx.x * 32, n0 = blockIdx.y * 32;
  const int t = threadIdx.x;
  const int i = t >> 3, j = (t & 7) * 4;
  float4 v = *(const float4*)(w + (size_t)(k0 + i) * Nn + n0 + j);
  tile[i][j] = v.x; tile[i][j + 1] = v.y; tile[i][j + 2] = v.z; tile[i][j + 3] = v.w;
  __syncthreads();
  const int n = i, k4 = j;
  u16x4 o;
  o[0] = f2bf(tile[k4 + 0][n]); o[1] = f2bf(tile[k4 + 1][n]);
  o[2] = f2bf(tile[k4 + 2][n]); o[3] = f2bf(tile[k4 + 3][n]);
  *(u16x4*)(wT + (size_t)(n0 + n) * Kk + k0 + k4) = o;
}

// ---------------- GEMM: C[M,Nx] = A[M,1024] @ Bt[Nx,1024]^T + bias ----------------
// EPI 0: fp32 row-major out.  EPI 1: scatter to Q/K bf16 (scaled) + V transposed.
template <int EPI>
__global__ __launch_bounds__(256) void k_gemm(const unsigned short* __restrict__ A,
                                              const unsigned short* __restrict__ Bt,
                                              const float* __restrict__ bias, int Nx,
                                              float* __restrict__ outF,
                                              unsigned short* __restrict__ Qb,
                                              unsigned short* __restrict__ Kb,
                                              unsigned short* __restrict__ Vb) {
  __shared__ unsigned short As[128][40];
  __shared__ unsigned short Bs[128][40];
  const int t = threadIdx.x;
  const int brow = blockIdx.x * 128, bcol = blockIdx.y * 128;
  const int lane = t & 63, wid = t >> 6;
  const int wr = (wid >> 1) * 64, wc = (wid & 1) * 64;
  const int g = lane >> 4, qr = lane & 15;
  const f32x4 fzero = {0.f, 0.f, 0.f, 0.f};
  f32x4 acc[4][4];
#pragma unroll
  for (int i = 0; i < 4; ++i)
#pragma unroll
    for (int n = 0; n < 4; ++n) acc[i][n] = fzero;
  const int r0 = t >> 2, koff = (t & 3) * 8;
  const unsigned short* Ap = A + (size_t)(brow + r0) * 1024 + koff;
  const unsigned short* Bp = Bt + (size_t)(bcol + r0) * 1024 + koff;
  for (int kt = 0; kt < 32; ++kt) {
    const int k0 = kt * 32;
    int4v av0 = *(const int4v*)(Ap + k0);
    int4v av1 = *(const int4v*)(Ap + 64 * 1024 + k0);
    int4v bv0 = *(const int4v*)(Bp + k0);
    int4v bv1 = *(const int4v*)(Bp + 64 * 1024 + k0);
    __syncthreads();
    *(int4v*)&As[r0][koff] = av0;
    *(int4v*)&As[r0 + 64][koff] = av1;
    *(int4v*)&Bs[r0][koff] = bv0;
    *(int4v*)&Bs[r0 + 64][koff] = bv1;
    __syncthreads();
    bf16x8 a[4], b[4];
#pragma unroll
    for (int i = 0; i < 4; ++i) a[i] = *(const bf16x8*)&As[wr + i * 16 + qr][g * 8];
#pragma unroll
    for (int n = 0; n < 4; ++n) b[n] = *(const bf16x8*)&Bs[wc + n * 16 + qr][g * 8];
#pragma unroll
    for (int i = 0; i < 4; ++i)
#pragma unroll
      for (int n = 0; n < 4; ++n)
        acc[i][n] = __builtin_amdgcn_mfma_f32_16x16x32_bf16(a[i], b[n], acc[i][n], 0, 0, 0);
  }
#pragma unroll
  for (int i = 0; i < 4; ++i) {
#pragma unroll
    for (int n = 0; n < 4; ++n) {
      const int col = bcol + wc + n * 16 + qr;
      const float bv = bias[col];
#pragma unroll
      for (int r = 0; r < 4; ++r) {
        const int row = brow + wr + i * 16 + g * 4 + r;
        const float v = acc[i][n][r] + bv;
        if constexpr (EPI == 0) {
          outF[(size_t)row * Nx + col] = v;
        } else {
          const int bb = row >> 11, tkn = row & 2047;
          const unsigned c = (unsigned)col;
          const unsigned h = c / 192u;
          const unsigned rem = c - h * 192u;
          const unsigned which = rem >> 6, d = rem & 63u;
          const float sc = (which < 2u) ? 0.35355339059327373f : 1.0f;
          const unsigned short u = f2bf(v * sc);
          if (which == 0u)
            Qb[(size_t)(((unsigned)bb * 16u + h) * 2048u + (unsigned)tkn) * 64u + d] = u;
          else if (which == 1u)
            Kb[(size_t)(((unsigned)bb * 16u + h) * 2048u + (unsigned)tkn) * 64u + d] = u;
          else  // V transposed: [bh][d][tkn]
            Vb[(size_t)(((unsigned)bb * 16u + h) * 64u + d) * 2048u + (unsigned)tkn] = u;
        }
      }
    }
  }
}

// ---------------- flash attention: 4 waves x 32 q-rows, KVBLK=64, LDS-staged ----------------
__global__ __launch_bounds__(256) void k_attn(const unsigned short* __restrict__ Qb,
                                              const unsigned short* __restrict__ Kb,
                                              const unsigned short* __restrict__ Vt,
                                              unsigned short* __restrict__ Ao) {
  __shared__ unsigned short Kl[2][64][64];   // [buf][key][d], XOR-swizzled rows
  __shared__ unsigned short Vl[2][64][64];   // [buf][d][key], XOR-swizzled rows
  __shared__ unsigned short Pl[4][2][16][72];  // per-wave, per-group P bounce
  const int bid = blockIdx.x;
  const int bh = (bid & 7) * 8 + ((bid >> 3) >> 4);  // XCD-major: XCD x owns bh x*8..x*8+7
  const int qt = (bid >> 3) & 15;
  const int t = threadIdx.x, lane = t & 63, w = t >> 6;
  const int g = lane >> 4, q = lane & 15;
  const int q0 = qt * 128 + w * 32;
  const unsigned short* Qbase = Qb + ((size_t)bh * 2048 + q0) * 64;
  const char* Kg = (const char*)(Kb + (size_t)bh * 2048 * 64);
  const char* Vg = (const char*)(Vt + (size_t)bh * 64 * 2048);
  // staging: per-lane pre-swizzled global source, linear LDS dest (m173 pattern)
  const int lr = lane >> 3, lc = lane & 7;
  const int swz = (lc ^ lr) << 4;
  const int c0 = 2 * w, c1 = c0 + 1;  // this wave's 1KB chunks (of 8 per tile)
  const char* Ks0 = Kg + c0 * 1024 + lr * 128 + swz;
  const char* Ks1 = Kg + c1 * 1024 + lr * 128 + swz;
  const char* Vs0 = Vg + (c0 * 8 + lr) * 4096 + swz;
  const char* Vs1 = Vg + (c1 * 8 + lr) * 4096 + swz;

#define STAGE(buf, it_)                                      \
  do {                                                       \
    gl_lds16(Ks0 + (it_) * 8192, &Kl[buf][c0 * 8][0]);       \
    gl_lds16(Ks1 + (it_) * 8192, &Kl[buf][c1 * 8][0]);       \
    gl_lds16(Vs0 + (it_) * 128, &Vl[buf][c0 * 8][0]);        \
    gl_lds16(Vs1 + (it_) * 128, &Vl[buf][c1 * 8][0]);        \
  } while (0)

  bf16x8 qf[2][2];
#pragma unroll
  for (int G = 0; G < 2; ++G)
#pragma unroll
    for (int h = 0; h < 2; ++h)
      qf[G][h] = *(const bf16x8*)(Qbase + (size_t)(G * 16 + q) * 64 + h * 32 + g * 8);
  const f32x4 fzero = {0.f, 0.f, 0.f, 0.f};
  f32x4 o0[4], o1[4];
#pragma unroll
  for (int i = 0; i < 4; ++i) { o0[i] = fzero; o1[i] = fzero; }
  float m0 = -1e30f, l0 = 0.f, m1 = -1e30f, l1 = 0.f;

  STAGE(0, 0);
  __syncthreads();

  for (int it = 0; it < 32; ++it) {
    const int cur = it & 1;
    if (it < 31) STAGE(cur ^ 1, it + 1);
    // ---- QK^T (swapped: A=K rows=keys, B=Q cols=queries) ----
    f32x4 s0[4], s1[4];
    __builtin_amdgcn_s_setprio(1);
#pragma unroll
    for (int kf = 0; kf < 4; ++kf) {
      const int row = kf * 16 + q;
      const char* kp = (const char*)&Kl[cur][row][0];
      const int sw = (row & 7) << 4;
      bf16x8 kaL = *(const bf16x8*)(kp + ((g * 16) ^ sw));
      bf16x8 kaH = *(const bf16x8*)(kp + ((64 + g * 16) ^ sw));
      s0[kf] = __builtin_amdgcn_mfma_f32_16x16x32_bf16(kaL, qf[0][0], fzero, 0, 0, 0);
      s0[kf] = __builtin_amdgcn_mfma_f32_16x16x32_bf16(kaH, qf[0][1], s0[kf], 0, 0, 0);
      s1[kf] = __builtin_amdgcn_mfma_f32_16x16x32_bf16(kaL, qf[1][0], fzero, 0, 0, 0);
      s1[kf] = __builtin_amdgcn_mfma_f32_16x16x32_bf16(kaH, qf[1][1], s1[kf], 0, 0, 0);
    }
    __builtin_amdgcn_s_setprio(0);
    // ---- online softmax, group 0 ----
    {
      float mt = -1e30f;
#pragma unroll
      for (int kf = 0; kf < 4; ++kf)
#pragma unroll
        for (int r = 0; r < 4; ++r) mt = fmaxf(mt, s0[kf][r]);
      mt = fmaxf(mt, __shfl_xor(mt, 16));
      mt = fmaxf(mt, __shfl_xor(mt, 32));
      const float mnew = fmaxf(m0, mt);
      const float al = __expf(m0 - mnew);
      float ts = 0.f, pv[16];
#pragma unroll
      for (int kf = 0; kf < 4; ++kf)
#pragma unroll
        for (int r = 0; r < 4; ++r) { float e = __expf(s0[kf][r] - mnew); pv[kf * 4 + r] = e; ts += e; }
      ts += __shfl_xor(ts, 16);
      ts += __shfl_xor(ts, 32);
      l0 = l0 * al + ts; m0 = mnew;
#pragma unroll
      for (int kf = 0; kf < 4; ++kf) {
        unsigned lo = (unsigned)f2bf(pv[kf * 4]) | ((unsigned)f2bf(pv[kf * 4 + 1]) << 16);
        unsigned hi = (unsigned)f2bf(pv[kf * 4 + 2]) | ((unsigned)f2bf(pv[kf * 4 + 3]) << 16);
        *(unsigned*)&Pl[w][0][q][kf * 16 + 4 * g] = lo;
        *(unsigned*)&Pl[w][0][q][kf * 16 + 4 * g + 2] = hi;
      }
      const float a0 = __shfl(al, 4 * g + 0), a1 = __shfl(al, 4 * g + 1);
      const float a2 = __shfl(al, 4 * g + 2), a3 = __shfl(al, 4 * g + 3);
#pragma unroll
      for (int i = 0; i < 4; ++i) { o0[i][0] *= a0; o0[i][1] *= a1; o0[i][2] *= a2; o0[i][3] *= a3; }
    }
    // ---- online softmax, group 1 ----
    {
      float mt = -1e30f;
#pragma unroll
      for (int kf = 0; kf < 4; ++kf)
#pragma unroll
        for (int r = 0; r < 4; ++r) mt = fmaxf(mt, s1[kf][r]);
      mt = fmaxf(mt, __shfl_xor(mt, 16));
      mt = fmaxf(mt, __shfl_xor(mt, 32));
      const float mnew = fmaxf(m1, mt);
      const float al = __expf(m1 - mnew);
      float ts = 0.f, pv[16];
#pragma unroll
      for (int kf = 0; kf < 4; ++kf)
#pragma unroll
        for (int r = 0; r < 4; ++r) { float e = __expf(s1[kf][r] - mnew); pv[kf * 4 + r] = e; ts += e; }
      ts += __shfl_xor(ts, 16);
      ts += __shfl_xor(ts, 32);
      l1 = l1 * al + ts; m1 = mnew;
#pragma unroll
      for (int kf = 0; kf < 4; ++kf) {
        unsigned lo = (unsigned)f2bf(pv[kf * 4]) | ((unsigned)f2bf(pv[kf * 4 + 1]) << 16);
        unsigned hi = (unsigned)f2bf(pv[kf * 4 + 2]) | ((unsigned)f2bf(pv[kf * 4 + 3]) << 16);
        *(unsigned*)&Pl[w][1][q][kf * 16 + 4 * g] = lo;
        *(unsigned*)&Pl[w][1][q][kf * 16 + 4 * g + 2] = hi;
      }
      const float a0 = __shfl(al, 4 * g + 0), a1 = __shfl(al, 4 * g + 1);
      const float a2 = __shfl(al, 4 * g + 2), a3 = __shfl(al, 4 * g + 3);
#pragma unroll
      for (int i = 0; i < 4; ++i) { o1[i][0] *= a0; o1[i][1] *= a1; o1[i][2] *= a2; o1[i][3] *= a3; }
    }
    // ---- PV ----
    bf16x8 pa0[2], pa1[2];
#pragma unroll
    for (int h = 0; h < 2; ++h) {
      pa0[h] = *(const bf16x8*)&Pl[w][0][q][h * 32 + g * 8];
      pa1[h] = *(const bf16x8*)&Pl[w][1][q][h * 32 + g * 8];
    }
    __builtin_amdgcn_s_setprio(1);
#pragma unroll
    for (int dblk = 0; dblk < 4; ++dblk) {
      const int row = dblk * 16 + q;
      const char* vp = (const char*)&Vl[cur][row][0];
      const int sw = (row & 7) << 4;
      bf16x8 vL = *(const bf16x8*)(vp + ((g * 16) ^ sw));
      bf16x8 vH = *(const bf16x8*)(vp + ((64 + g * 16) ^ sw));
      o0[dblk] = __builtin_amdgcn_mfma_f32_16x16x32_bf16(pa0[0], vL, o0[dblk], 0, 0, 0);
      o0[dblk] = __builtin_amdgcn_mfma_f32_16x16x32_bf16(pa0[1], vH, o0[dblk], 0, 0, 0);
      o1[dblk] = __builtin_amdgcn_mfma_f32_16x16x32_bf16(pa1[0], vL, o1[dblk], 0, 0, 0);
      o1[dblk] = __builtin_amdgcn_mfma_f32_16x16x32_bf16(pa1[1], vH, o1[dblk], 0, 0, 0);
    }
    __builtin_amdgcn_s_setprio(0);
    __syncthreads();
  }
#undef STAGE
  const int bb = bh >> 4, hh = bh & 15;
  {
    const float linv = 1.0f / l0;
    float rr[4];
    rr[0] = __shfl(linv, 4 * g + 0); rr[1] = __shfl(linv, 4 * g + 1);
    rr[2] = __shfl(linv, 4 * g + 2); rr[3] = __shfl(linv, 4 * g + 3);
    unsigned short* ob = Ao + ((size_t)bb * 2048 + q0 + 4 * g) * 1024 + hh * 64 + q;
#pragma unroll
    for (int dblk = 0; dblk < 4; ++dblk)
#pragma unroll
      for (int r = 0; r < 4; ++r)
        ob[(size_t)r * 1024 + dblk * 16] = f2bf(o0[dblk][r] * rr[r]);
  }
  {
    const float linv = 1.0f / l1;
    float rr[4];
    rr[0] = __shfl(linv, 4 * g + 0); rr[1] = __shfl(linv, 4 * g + 1);
    rr[2] = __shfl(linv, 4 * g + 2); rr[3] = __shfl(linv, 4 * g + 3);
    unsigned short* ob = Ao + ((size_t)bb * 2048 + q0 + 16 + 4 * g) * 1024 + hh * 64 + q;
#pragma unroll
    for (int dblk = 0; dblk < 4; ++dblk)
#pragma unroll
      for (int r = 0; r < 4; ++r)
        ob[(size_t)r * 1024 + dblk * 16] = f2bf(o1[dblk][r] * rr[r]);
  }
}

extern "C" void kernel_launch(void* const* d_in, const int* in_sizes, int n_in,
                              void* d_out, int out_size, void* d_ws, size_t ws_size,
                              hipStream_t stream) {
  const float* x = (const float*)d_in[0];
  const float* w_qkv = (const float*)d_in[1];
  const float* b_qkv = (const float*)d_in[2];
  const float* w_proj = (const float*)d_in[3];
  const float* b_proj = (const float*)d_in[4];
  float* out = (float*)d_out;
  char* ws = (char*)d_ws;
  unsigned short* xb = (unsigned short*)(ws);                  // 16 MB  [8192,1024] bf16
  unsigned short* wqkvT = (unsigned short*)(ws + 16777216);    // 6 MB   [3072,1024]
  unsigned short* wprojT = (unsigned short*)(ws + 23068672);   // 2 MB   [1024,1024]
  unsigned short* Qb = (unsigned short*)(ws + 25165824);       // 16 MB  [bh][2048][64]
  unsigned short* Kb = (unsigned short*)(ws + 41943040);       // 16 MB  [bh][2048][64]
  unsigned short* Vt = (unsigned short*)(ws + 58720256);       // 16 MB  [bh][64][2048]
  unsigned short* Ao = xb;  // reuse (xb dead after GEMM1)

  hipLaunchKernelGGL(k_cvt, dim3(4096), dim3(256), 0, stream, x, xb);
  hipLaunchKernelGGL(k_wT, dim3(32, 96), dim3(256), 0, stream, w_qkv, wqkvT, 3072, 1024);
  hipLaunchKernelGGL(k_wT, dim3(32, 32), dim3(256), 0, stream, w_proj, wprojT, 1024, 1024);
  hipLaunchKernelGGL((k_gemm<1>), dim3(64, 24), dim3(256), 0, stream,
                     xb, wqkvT, b_qkv, 3072, (float*)nullptr, Qb, Kb, Vt);
  hipLaunchKernelGGL(k_attn, dim3(1024), dim3(256), 0, stream, Qb, Kb, Vt, Ao);
  hipLaunchKernelGGL((k_gemm<0>), dim3(64, 8), dim3(256), 0, stream,
                     Ao, wprojT, b_proj, 1024, out,
                     (unsigned short*)nullptr, (unsigned short*)nullptr, (unsigned short*)nullptr);
}

// Round 3
// 209.560 us; speedup vs baseline: 2.7963x; 1.3502x over previous
//
#include <hip/hip_runtime.h>

typedef __attribute__((ext_vector_type(8))) short bf16x8;   // MFMA A/B frag (8 bf16)
typedef __attribute__((ext_vector_type(4))) float f32x4;    // MFMA C/D frag
typedef __attribute__((ext_vector_type(8))) unsigned short u16x8;
typedef __attribute__((ext_vector_type(4))) unsigned short u16x4;
typedef __attribute__((ext_vector_type(2))) unsigned u32x2;

__device__ __forceinline__ unsigned short f2bf(float f) {
  unsigned u = __builtin_bit_cast(unsigned, f);
  return (unsigned short)((u + 0x7fffu + ((u >> 16) & 1u)) >> 16);
}

__device__ __forceinline__ unsigned cvt_pk_bf16(float lo, float hi) {
  unsigned r;
  asm("v_cvt_pk_bf16_f32 %0, %1, %2" : "=v"(r) : "v"(lo), "v"(hi));
  return r;
}

__device__ __forceinline__ void gl_lds16(const void* g, void* l) {
  __builtin_amdgcn_global_load_lds((const __attribute__((address_space(1))) unsigned*)g,
                                   (__attribute__((address_space(3))) unsigned*)l, 16, 0, 0);
}

// ---------------- convert x fp32 -> bf16, 8 elems/thread ----------------
__global__ __launch_bounds__(256) void k_cvt(const float* __restrict__ x,
                                             unsigned short* __restrict__ xb) {
  int i = blockIdx.x * 256 + threadIdx.x;
  const float4* s = (const float4*)x;
  float4 a = s[2 * i], b = s[2 * i + 1];
  u16x8 o;
  o[0] = f2bf(a.x); o[1] = f2bf(a.y); o[2] = f2bf(a.z); o[3] = f2bf(a.w);
  o[4] = f2bf(b.x); o[5] = f2bf(b.y); o[6] = f2bf(b.z); o[7] = f2bf(b.w);
  *(u16x8*)(xb + 8 * (size_t)i) = o;
}

// ------------- transpose+convert weight [K][N] f32 -> [N][K] bf16 -------------
__global__ __launch_bounds__(256) void k_wT(const float* __restrict__ w,
                                            unsigned short* __restrict__ wT,
                                            int Nn, int Kk) {
  __shared__ float tile[32][33];
  const int k0 = blockIdx.x * 32, n0 = blockIdx.y * 32;
  const int t = threadIdx.x;
  const int i = t >> 3, j = (t & 7) * 4;
  float4 v = *(const float4*)(w + (size_t)(k0 + i) * Nn + n0 + j);
  tile[i][j] = v.x; tile[i][j + 1] = v.y; tile[i][j + 2] = v.z; tile[i][j + 3] = v.w;
  __syncthreads();
  const int n = i, k4 = j;
  u16x4 o;
  o[0] = f2bf(tile[k4 + 0][n]); o[1] = f2bf(tile[k4 + 1][n]);
  o[2] = f2bf(tile[k4 + 2][n]); o[3] = f2bf(tile[k4 + 3][n]);
  *(u16x4*)(wT + (size_t)(n0 + n) * Kk + k0 + k4) = o;
}

// ---------------- GEMM: C[M,Nx] = A[M,1024] @ Bt[Nx,1024]^T + bias ----------------
// m97 structure: global_load_lds w=16, linear LDS, 128x128 tile, BK=32.
// EPI 0: fp32 row-major out.  EPI 1: scatter to Q/K bf16 (scaled) + V transposed.
template <int EPI>
__global__ __launch_bounds__(256) void k_gemm(const unsigned short* __restrict__ A,
                                              const unsigned short* __restrict__ Bt,
                                              const float* __restrict__ bias, int Nx,
                                              float* __restrict__ outF,
                                              unsigned short* __restrict__ Qb,
                                              unsigned short* __restrict__ Kb,
                                              unsigned short* __restrict__ Vb) {
  __shared__ unsigned short As[128 * 32];
  __shared__ unsigned short Bs[128 * 32];
  const int t = threadIdx.x;
  const int brow = blockIdx.x * 128, bcol = blockIdx.y * 128;
  const int lane = t & 63, wid = t >> 6;
  const int wr = (wid >> 1) * 64, wc = (wid & 1) * 64;
  const int g = lane >> 4, qr = lane & 15;
  const f32x4 fzero = {0.f, 0.f, 0.f, 0.f};
  f32x4 acc[4][4];
#pragma unroll
  for (int i = 0; i < 4; ++i)
#pragma unroll
    for (int n = 0; n < 4; ++n) acc[i][n] = fzero;
  // staging: thread t -> tile row t/4, k-chunk (t&3)*8 elems; LDS linear byte t*16
  const unsigned short* Ag = A + (size_t)(brow + (t >> 2)) * 1024 + (t & 3) * 8;
  const unsigned short* Bg = Bt + (size_t)(bcol + (t >> 2)) * 1024 + (t & 3) * 8;
  unsigned short* Asl = As + t * 8;
  unsigned short* Bsl = Bs + t * 8;
  for (int kt = 0; kt < 32; ++kt) {
    const int k0 = kt * 32;
    gl_lds16(Ag + k0, Asl);
    gl_lds16(Ag + 64 * 1024 + k0, Asl + 2048);
    gl_lds16(Bg + k0, Bsl);
    gl_lds16(Bg + 64 * 1024 + k0, Bsl + 2048);
    __syncthreads();
    bf16x8 a[4], b[4];
#pragma unroll
    for (int i = 0; i < 4; ++i) a[i] = *(const bf16x8*)&As[(wr + i * 16 + qr) * 32 + g * 8];
#pragma unroll
    for (int n = 0; n < 4; ++n) b[n] = *(const bf16x8*)&Bs[(wc + n * 16 + qr) * 32 + g * 8];
#pragma unroll
    for (int i = 0; i < 4; ++i)
#pragma unroll
      for (int n = 0; n < 4; ++n)
        acc[i][n] = __builtin_amdgcn_mfma_f32_16x16x32_bf16(a[i], b[n], acc[i][n], 0, 0, 0);
    __syncthreads();
  }
#pragma unroll
  for (int i = 0; i < 4; ++i) {
#pragma unroll
    for (int n = 0; n < 4; ++n) {
      const int col = bcol + wc + n * 16 + qr;
      const float bv = bias[col];
      float v4[4];
#pragma unroll
      for (int r = 0; r < 4; ++r) v4[r] = acc[i][n][r] + bv;
      const int row0 = brow + wr + i * 16 + g * 4;
      if constexpr (EPI == 0) {
#pragma unroll
        for (int r = 0; r < 4; ++r) outF[(size_t)(row0 + r) * Nx + col] = v4[r];
      } else {
        const int bb = row0 >> 11, tkn0 = row0 & 2047;
        const unsigned c = (unsigned)col;
        const unsigned h = c / 192u;
        const unsigned rem = c - h * 192u;
        const unsigned which = rem >> 6, d = rem & 63u;
        if (which == 2u) {  // V transposed [bh][d][tkn]: 4 consecutive tokens -> 8B store
          u16x4 pk;
#pragma unroll
          for (int r = 0; r < 4; ++r) pk[r] = f2bf(v4[r]);
          *(u16x4*)&Vb[(size_t)(((unsigned)bb * 16u + h) * 64u + d) * 2048u + (unsigned)tkn0] = pk;
        } else {
          // Q gets extra log2e fold (softmax computed in exp2 domain)
          const float sc = (which == 0u) ? (0.35355339059327373f * 1.4426950408889634f)
                                         : 0.35355339059327373f;
          unsigned short* dst = (which == 0u) ? Qb : Kb;
#pragma unroll
          for (int r = 0; r < 4; ++r)
            dst[(size_t)(((unsigned)bb * 16u + h) * 2048u + (unsigned)(tkn0 + r)) * 64u + d] =
                f2bf(v4[r] * sc);
        }
      }
    }
  }
}

// -------- flash attention: 8 waves x 16 q-rows, KVBLK=64, LDS dbuf, exp2 softmax --------
__global__ __launch_bounds__(512, 6) void k_attn(const unsigned short* __restrict__ Qb,
                                                 const unsigned short* __restrict__ Kb,
                                                 const unsigned short* __restrict__ Vt,
                                                 unsigned short* __restrict__ Ao) {
  __shared__ unsigned short Kl[2][64][64];   // [buf][key][d], content XOR-swizzled per row
  __shared__ unsigned short Vl[2][64][64];   // [buf][d][key], content XOR-swizzled per row
  __shared__ unsigned short Pl[8][16][72];   // per-wave P bounce, row stride 144B
  const int bid = blockIdx.x;
  const int bh = (bid & 7) * 8 + ((bid >> 3) >> 4);  // XCD x owns bh x*8..x*8+7
  const int qt = (bid >> 3) & 15;
  const int t = threadIdx.x, lane = t & 63, w = t >> 6;  // 8 waves
  const int g = lane >> 4, q = lane & 15;
  const int q0 = qt * 128 + w * 16;
  const unsigned short* Qbase = Qb + ((size_t)bh * 2048 + q0) * 64;
  const char* Kg = (const char*)(Kb + (size_t)bh * 2048 * 64);
  const char* Vg = (const char*)(Vt + (size_t)bh * 64 * 2048);
  // staging: wave w stages rows 8w..8w+7 of K and of V(d); pre-swizzled global src
  const int lr = lane >> 3, lc = lane & 7;
  const int swz = (lc ^ lr) << 4;
  const char* Ksrc = Kg + (size_t)(8 * w + lr) * 128 + swz;
  const char* Vsrc = Vg + (size_t)(8 * w + lr) * 4096 + swz;
  unsigned short* Kd0 = &Kl[0][8 * w][0] + lane * 8;
  unsigned short* Kd1 = &Kl[1][8 * w][0] + lane * 8;
  unsigned short* Vd0 = &Vl[0][8 * w][0] + lane * 8;
  unsigned short* Vd1 = &Vl[1][8 * w][0] + lane * 8;

  bf16x8 qf0 = *(const bf16x8*)(Qbase + (size_t)q * 64 + g * 8);
  bf16x8 qf1 = *(const bf16x8*)(Qbase + (size_t)q * 64 + 32 + g * 8);
  const f32x4 fzero = {0.f, 0.f, 0.f, 0.f};
  f32x4 o[4];
#pragma unroll
  for (int i = 0; i < 4; ++i) o[i] = fzero;
  float m = -1e30f, l = 0.f;

  gl_lds16(Ksrc, Kd0);
  gl_lds16(Vsrc, Vd0);
  __syncthreads();

  for (int it = 0; it < 32; ++it) {
    const int cur = it & 1;
    if (it < 31) {
      const size_t nx = (size_t)(it + 1);
      gl_lds16(Ksrc + nx * 8192, cur ? Kd0 : Kd1);
      gl_lds16(Vsrc + nx * 128, cur ? Vd0 : Vd1);
    }
    // ---- QK^T (swapped: A=K rows=keys, B=Q cols=queries) ----
    f32x4 s[4];
    __builtin_amdgcn_s_setprio(1);
#pragma unroll
    for (int kf = 0; kf < 4; ++kf) {
      const int row = kf * 16 + q;
      const char* kp = (const char*)&Kl[cur][row][0];
      const int sw = (row & 7) << 4;
      bf16x8 kaL = *(const bf16x8*)(kp + ((g * 16) ^ sw));
      bf16x8 kaH = *(const bf16x8*)(kp + ((64 + g * 16) ^ sw));
      s[kf] = __builtin_amdgcn_mfma_f32_16x16x32_bf16(kaL, qf0, fzero, 0, 0, 0);
      s[kf] = __builtin_amdgcn_mfma_f32_16x16x32_bf16(kaH, qf1, s[kf], 0, 0, 0);
    }
    __builtin_amdgcn_s_setprio(0);
    // ---- online softmax (exp2 domain; defer-max THR=11.5) ----
    float mt = fmaxf(fmaxf(fmaxf(s[0][0], s[0][1]), fmaxf(s[0][2], s[0][3])),
                     fmaxf(fmaxf(s[1][0], s[1][1]), fmaxf(s[1][2], s[1][3])));
    mt = fmaxf(mt, fmaxf(fmaxf(fmaxf(s[2][0], s[2][1]), fmaxf(s[2][2], s[2][3])),
                         fmaxf(fmaxf(s[3][0], s[3][1]), fmaxf(s[3][2], s[3][3]))));
    mt = fmaxf(mt, __shfl_xor(mt, 16));
    mt = fmaxf(mt, __shfl_xor(mt, 32));
    if (!__all(mt - m <= 11.5f)) {
      const float mnew = fmaxf(m, mt);
      const float al = __builtin_amdgcn_exp2f(m - mnew);
      const float a0 = __shfl(al, 4 * g + 0), a1 = __shfl(al, 4 * g + 1);
      const float a2 = __shfl(al, 4 * g + 2), a3 = __shfl(al, 4 * g + 3);
#pragma unroll
      for (int i = 0; i < 4; ++i) { o[i][0] *= a0; o[i][1] *= a1; o[i][2] *= a2; o[i][3] *= a3; }
      l *= al;
      m = mnew;
    }
    unsigned short* Pw = &Pl[w][q][0];
    float ts = 0.f;
#pragma unroll
    for (int kf = 0; kf < 4; ++kf) {
      const float e0 = __builtin_amdgcn_exp2f(s[kf][0] - m);
      const float e1 = __builtin_amdgcn_exp2f(s[kf][1] - m);
      const float e2 = __builtin_amdgcn_exp2f(s[kf][2] - m);
      const float e3 = __builtin_amdgcn_exp2f(s[kf][3] - m);
      ts += (e0 + e1) + (e2 + e3);
      u32x2 pk;
      pk[0] = cvt_pk_bf16(e0, e1);
      pk[1] = cvt_pk_bf16(e2, e3);
      *(u32x2*)(Pw + (8 * kf + 2 * g) * 2) = pk;  // keys 16kf+4g..+3
    }
    ts += __shfl_xor(ts, 16);
    ts += __shfl_xor(ts, 32);
    l += ts;
    asm volatile("" ::: "memory");
    // ---- PV ----
    const bf16x8 pa0 = *(const bf16x8*)&Pl[w][q][g * 8];        // keys 8g..8g+7
    const bf16x8 pa1 = *(const bf16x8*)&Pl[w][q][32 + g * 8];   // keys 32+8g..+7
    __builtin_amdgcn_s_setprio(1);
#pragma unroll
    for (int dblk = 0; dblk < 4; ++dblk) {
      const int row = dblk * 16 + q;
      const char* vp = (const char*)&Vl[cur][row][0];
      const int sw = (row & 7) << 4;
      bf16x8 vL = *(const bf16x8*)(vp + ((g * 16) ^ sw));
      bf16x8 vH = *(const bf16x8*)(vp + ((64 + g * 16) ^ sw));
      o[dblk] = __builtin_amdgcn_mfma_f32_16x16x32_bf16(pa0, vL, o[dblk], 0, 0, 0);
      o[dblk] = __builtin_amdgcn_mfma_f32_16x16x32_bf16(pa1, vH, o[dblk], 0, 0, 0);
    }
    __builtin_amdgcn_s_setprio(0);
    __syncthreads();
  }
  const float linv = 1.0f / l;
  float rr[4];
  rr[0] = __shfl(linv, 4 * g + 0); rr[1] = __shfl(linv, 4 * g + 1);
  rr[2] = __shfl(linv, 4 * g + 2); rr[3] = __shfl(linv, 4 * g + 3);
  const int bb = bh >> 4, hh = bh & 15;
  unsigned short* ob = Ao + ((size_t)bb * 2048 + q0 + 4 * g) * 1024 + hh * 64 + q;
#pragma unroll
  for (int dblk = 0; dblk < 4; ++dblk)
#pragma unroll
    for (int r = 0; r < 4; ++r)
      ob[(size_t)r * 1024 + dblk * 16] = f2bf(o[dblk][r] * rr[r]);
}

extern "C" void kernel_launch(void* const* d_in, const int* in_sizes, int n_in,
                              void* d_out, int out_size, void* d_ws, size_t ws_size,
                              hipStream_t stream) {
  const float* x = (const float*)d_in[0];
  const float* w_qkv = (const float*)d_in[1];
  const float* b_qkv = (const float*)d_in[2];
  const float* w_proj = (const float*)d_in[3];
  const float* b_proj = (const float*)d_in[4];
  float* out = (float*)d_out;
  char* ws = (char*)d_ws;
  unsigned short* xb = (unsigned short*)(ws);                  // 16 MB  [8192,1024] bf16
  unsigned short* wqkvT = (unsigned short*)(ws + 16777216);    // 6 MB   [3072,1024]
  unsigned short* wprojT = (unsigned short*)(ws + 23068672);   // 2 MB   [1024,1024]
  unsigned short* Qb = (unsigned short*)(ws + 25165824);       // 16 MB  [bh][2048][64] (log2e folded)
  unsigned short* Kb = (unsigned short*)(ws + 41943040);       // 16 MB  [bh][2048][64]
  unsigned short* Vt = (unsigned short*)(ws + 58720256);       // 16 MB  [bh][64][2048]
  unsigned short* Ao = xb;  // reuse (xb dead after GEMM1)

  hipLaunchKernelGGL(k_cvt, dim3(4096), dim3(256), 0, stream, x, xb);
  hipLaunchKernelGGL(k_wT, dim3(32, 96), dim3(256), 0, stream, w_qkv, wqkvT, 3072, 1024);
  hipLaunchKernelGGL(k_wT, dim3(32, 32), dim3(256), 0, stream, w_proj, wprojT, 1024, 1024);
  hipLaunchKernelGGL((k_gemm<1>), dim3(64, 24), dim3(256), 0, stream,
                     xb, wqkvT, b_qkv, 3072, (float*)nullptr, Qb, Kb, Vt);
  hipLaunchKernelGGL(k_attn, dim3(1024), dim3(512), 0, stream, Qb, Kb, Vt, Ao);
  hipLaunchKernelGGL((k_gemm<0>), dim3(64, 8), dim3(256), 0, stream,
                     Ao, wprojT, b_proj, 1024, out,
                     (unsigned short*)nullptr, (unsigned short*)nullptr, (unsigned short*)nullptr);
}